// Round 1
// baseline (315.055 us; speedup 1.0000x reference)
//
#include <hip/hip_runtime.h>
#include <math.h>

#define B 4096
#define D 512
#define MARGIN 0.3f
#define EPSD 1e-12f

#define NSEG 8
#define ROWTILE 128
#define CTILE 128
#define COLSEG (B / NSEG)   // 512
#define BK 32

// ---------------------------------------------------------------------------
// Kernel 1: squared norms, one wave (64 lanes) per row. 512 floats = 2 float4/lane.
// ---------------------------------------------------------------------------
__global__ __launch_bounds__(256) void sqnorm_kernel(const float* __restrict__ E,
                                                     float* __restrict__ sq) {
    int w    = (blockIdx.x * 256 + threadIdx.x) >> 6;   // row index
    int lane = threadIdx.x & 63;
    const float4* row = (const float4*)(E + (size_t)w * D);
    float4 a = row[lane];
    float4 b = row[lane + 64];
    float s = a.x * a.x + a.y * a.y + a.z * a.z + a.w * a.w
            + b.x * b.x + b.y * b.y + b.z * b.z + b.w * b.w;
#pragma unroll
    for (int o = 32; o; o >>= 1) s += __shfl_down(s, o);
    if (lane == 0) sq[w] = s;
}

// ---------------------------------------------------------------------------
// Kernel 2: fused distance + batch-hard mining.
// Grid: 32 row-tiles x 8 column segments = 256 blocks, 256 threads.
// Each block: 128 rows x 512 cols. Register tile 8x8 per thread (4+4 split).
// ---------------------------------------------------------------------------
__global__ __launch_bounds__(256) void mine_kernel(const float* __restrict__ E,
                                                   const int* __restrict__ labels,
                                                   const float* __restrict__ sq,
                                                   float* __restrict__ hp_part,
                                                   float* __restrict__ hn_part) {
    __shared__ float a_t[BK][ROWTILE + 4];
    __shared__ float b_t[BK][CTILE + 4];
    __shared__ float sqc_s[CTILE];
    __shared__ int   lab_s[CTILE];

    const int tid     = threadIdx.x;
    const int tx      = tid & 15;
    const int ty      = tid >> 4;
    const int rowTile = blockIdx.x & 31;
    const int seg     = blockIdx.x >> 5;
    const int r0      = rowTile * ROWTILE;
    const int c0      = seg * COLSEG;

    // my 8 rows: ty*4 + (i&3) + (i>>2)*64
    float hp[8], hn[8];
    float sq_i[8];
    int   lab_i[8];
#pragma unroll
    for (int i = 0; i < 8; ++i) {
        int rl = ty * 4 + (i & 3) + (i >> 2) * 64;
        hp[i] = -INFINITY;
        hn[i] = INFINITY;
        sq_i[i]  = sq[r0 + rl];
        lab_i[i] = labels[r0 + rl];
    }

    for (int ct = 0; ct < COLSEG / CTILE; ++ct) {
        const int c = c0 + ct * CTILE;
        __syncthreads();   // previous epilogue done reading lab_s/sqc_s
        if (tid < CTILE) {
            sqc_s[tid] = sq[c + tid];
            lab_s[tid] = labels[c + tid];
        }

        float acc[8][8];
#pragma unroll
        for (int i = 0; i < 8; ++i)
#pragma unroll
            for (int j = 0; j < 8; ++j) acc[i][j] = 0.f;

        for (int kk = 0; kk < D; kk += BK) {
            __syncthreads();   // previous compute done reading a_t/b_t
            // stage A tile transposed: 128 rows x 32 k = 1024 float4, 4/thread
#pragma unroll
            for (int i = 0; i < 4; ++i) {
                int idx = tid + i * 256;
                int row = idx >> 3;
                int k4  = idx & 7;
                float4 v = *(const float4*)(E + (size_t)(r0 + row) * D + kk + k4 * 4);
                a_t[k4 * 4 + 0][row] = v.x;
                a_t[k4 * 4 + 1][row] = v.y;
                a_t[k4 * 4 + 2][row] = v.z;
                a_t[k4 * 4 + 3][row] = v.w;
            }
#pragma unroll
            for (int i = 0; i < 4; ++i) {
                int idx = tid + i * 256;
                int row = idx >> 3;
                int k4  = idx & 7;
                float4 v = *(const float4*)(E + (size_t)(c + row) * D + kk + k4 * 4);
                b_t[k4 * 4 + 0][row] = v.x;
                b_t[k4 * 4 + 1][row] = v.y;
                b_t[k4 * 4 + 2][row] = v.z;
                b_t[k4 * 4 + 3][row] = v.w;
            }
            __syncthreads();

#pragma unroll
            for (int k = 0; k < BK; ++k) {
                float4 a0 = *(const float4*)&a_t[k][ty * 4];
                float4 a1 = *(const float4*)&a_t[k][64 + ty * 4];
                float4 b0 = *(const float4*)&b_t[k][tx * 4];
                float4 b1 = *(const float4*)&b_t[k][64 + tx * 4];
                float av[8] = {a0.x, a0.y, a0.z, a0.w, a1.x, a1.y, a1.z, a1.w};
                float bv[8] = {b0.x, b0.y, b0.z, b0.w, b1.x, b1.y, b1.z, b1.w};
#pragma unroll
                for (int i = 0; i < 8; ++i)
#pragma unroll
                    for (int j = 0; j < 8; ++j) acc[i][j] += av[i] * bv[j];
            }
        }

        // epilogue for this 128x128 tile
#pragma unroll
        for (int i = 0; i < 8; ++i) {
            const int rl = ty * 4 + (i & 3) + (i >> 2) * 64;
            const int ri = r0 + rl;
            const float sqi = sq_i[i];
            const int   li  = lab_i[i];
#pragma unroll
            for (int j = 0; j < 8; ++j) {
                const int cl = tx * 4 + (j & 3) + (j >> 2) * 64;
                const int cj = c + cl;
                float d2   = sqi + sqc_s[cl] - 2.f * acc[i][j];
                float dist = sqrtf(fmaxf(d2, EPSD));
                bool same  = (li == lab_s[cl]);
                bool diag  = (ri == cj);
                if (same && !diag) hp[i] = fmaxf(hp[i], dist);
                if (!same)         hn[i] = fminf(hn[i], dist);
            }
        }
    }

    // reduce across tx (lane bits 0..3)
#pragma unroll
    for (int i = 0; i < 8; ++i) {
#pragma unroll
        for (int m = 1; m < 16; m <<= 1) {
            hp[i] = fmaxf(hp[i], __shfl_xor(hp[i], m));
            hn[i] = fminf(hn[i], __shfl_xor(hn[i], m));
        }
    }
    if (tx == 0) {
#pragma unroll
        for (int i = 0; i < 8; ++i) {
            int rl = ty * 4 + (i & 3) + (i >> 2) * 64;
            hp_part[seg * B + r0 + rl] = hp[i];
            hn_part[seg * B + r0 + rl] = hn[i];
        }
    }
}

// ---------------------------------------------------------------------------
// Kernel 3: combine segments, masked mean of relu(hp-hn+margin).
// ---------------------------------------------------------------------------
__global__ __launch_bounds__(256) void finalize_kernel(const float* __restrict__ hp_part,
                                                       const float* __restrict__ hn_part,
                                                       float* __restrict__ out) {
    const int tid = threadIdx.x;
    float sum = 0.f, cnt = 0.f;
    for (int r = tid; r < B; r += 256) {
        float hp = -INFINITY, hn = INFINITY;
#pragma unroll
        for (int s = 0; s < NSEG; ++s) {
            hp = fmaxf(hp, hp_part[s * B + r]);
            hn = fminf(hn, hn_part[s * B + r]);
        }
        bool valid = (hp > -INFINITY) && (hn < INFINITY);
        if (valid) {
            sum += fmaxf(hp - hn + MARGIN, 0.f);
            cnt += 1.f;
        }
    }
#pragma unroll
    for (int o = 32; o; o >>= 1) {
        sum += __shfl_down(sum, o);
        cnt += __shfl_down(cnt, o);
    }
    __shared__ float ssum[4], scnt[4];
    int lane = tid & 63, wv = tid >> 6;
    if (lane == 0) { ssum[wv] = sum; scnt[wv] = cnt; }
    __syncthreads();
    if (tid == 0) {
        float S = 0.f, C = 0.f;
#pragma unroll
        for (int i = 0; i < 4; ++i) { S += ssum[i]; C += scnt[i]; }
        out[0] = (C > 0.f) ? S / fmaxf(C, 1.f) : 0.f;
    }
}

// ---------------------------------------------------------------------------
extern "C" void kernel_launch(void* const* d_in, const int* in_sizes, int n_in,
                              void* d_out, int out_size, void* d_ws, size_t ws_size,
                              hipStream_t stream) {
    const float* E      = (const float*)d_in[0];
    const int*   labels = (const int*)d_in[1];
    float* out = (float*)d_out;
    float* ws  = (float*)d_ws;

    float* sq      = ws;                 // B floats
    float* hp_part = ws + B;             // NSEG*B floats
    float* hn_part = ws + B + NSEG * B;  // NSEG*B floats

    sqnorm_kernel<<<B / 4, 256, 0, stream>>>(E, sq);
    mine_kernel<<<256, 256, 0, stream>>>(E, labels, sq, hp_part, hn_part);
    finalize_kernel<<<1, 256, 0, stream>>>(hp_part, hn_part, out);
}